// Round 9
// baseline (158.231 us; speedup 1.0000x reference)
//
#include <hip/hip_runtime.h>

// KPConv fused, R9 = R8 + h-sparsity in the slot loop:
//  - per-row 15-bit e-mask (which kernel points have h>0) built in 1b from register
//    sign bits + shfl_xor(32); stored in LDS cem[] next to cpk[] at compaction.
//  - slot loop: em -> SGPR via readfirstlane; each e guarded by wave-uniform
//    `if (em & (1<<e))` (s_cbranch) around readlane+fmac. ~0.9 nonzero e per live
//    row vs 15 unconditional -> ~2100 VALU ops/wave removed. Exact same math
//    (skipped terms are identically zero). Pads have em=0 (body never runs).
//  - accumulators stay scalar float kfv[4][15] (AGPR-friendly; R6 lesson).
//  - phase 2: R4-verified split-bf16 MFMA GEMM, unchanged.

namespace {
constexpr int NQ   = 50000;
constexpr int MS   = 50000;
constexpr int KNN  = 32;
constexpr int KP   = 15;
constexpr int CIN  = 64;
constexpr int COUT = 128;
constexpr int QB   = 32;                 // queries per block (2 MFMA m-tiles)
constexpr int ROWS = KP * CIN;           // 960
constexpr int RND  = 3;
constexpr int RE   = 5;                  // kernel points per round
constexpr int KBR  = (RE * CIN) / 32;    // 10
constexpr int KBT  = ROWS / 32;          // 30
constexpr int ASTR = RE * CIN + 4;       // 324 dwords per kf row
constexpr float KP_EXT_INV = 1.0f / 1.2f;
constexpr int OF_CPK = 0;                // 8 waves * 32 ints
constexpr int OF_CEM = 256;              // 8 waves * 32 ints
constexpr int OF_KP  = 512;              // 45
constexpr size_t WSB_HI  = 200704;
constexpr size_t WSB_LO  = 446464;
constexpr size_t WSB_END = 692224;
}

typedef __attribute__((ext_vector_type(8))) short short8;
typedef __attribute__((ext_vector_type(4))) float f32x4;
typedef __attribute__((ext_vector_type(4))) unsigned int u32x4;

__device__ __forceinline__ short f32_bf16(float x) {
    unsigned u = __builtin_bit_cast(unsigned, x);
    u = u + 0x7fffu + ((u >> 16) & 1u);
    return (short)(u >> 16);
}
__device__ __forceinline__ float bf16_f32(short h) {
    unsigned u = ((unsigned)(unsigned short)h) << 16;
    return __builtin_bit_cast(float, u);
}
__device__ __forceinline__ unsigned pack_hilo(float x) {
    unsigned xu = __builtin_bit_cast(unsigned, x);
    unsigned r  = xu + 0x7fffu + ((xu >> 16) & 1u);
    unsigned hi = r & 0xffff0000u;
    float lof = x - __builtin_bit_cast(float, hi);
    unsigned lu = __builtin_bit_cast(unsigned, lof);
    unsigned r2 = lu + 0x7fffu + ((lu >> 16) & 1u);
    return hi | (r2 >> 16);
}
__device__ __forceinline__ unsigned permb(unsigned a, unsigned b, unsigned sel) {
#if __has_builtin(__builtin_amdgcn_perm)
    return __builtin_amdgcn_perm(a, b, sel);
#else
    if (sel == 0x07060302u) return (a & 0xffff0000u) | (b >> 16);
    return (a << 16) | (b & 0xffffu);
#endif
}
__device__ __forceinline__ void unpack8(uint4 a, uint4 b, short8& hi, short8& lo) {
    u32x4 h, l;
    h[0] = permb(a.y, a.x, 0x07060302u); l[0] = permb(a.y, a.x, 0x05040100u);
    h[1] = permb(a.w, a.z, 0x07060302u); l[1] = permb(a.w, a.z, 0x05040100u);
    h[2] = permb(b.y, b.x, 0x07060302u); l[2] = permb(b.y, b.x, 0x05040100u);
    h[3] = permb(b.w, b.z, 0x07060302u); l[3] = permb(b.w, b.z, 0x05040100u);
    hi = __builtin_bit_cast(short8, h);
    lo = __builtin_bit_cast(short8, l);
}
__device__ __forceinline__ float readlane_f(float v, int l) {
    return __builtin_bit_cast(float,
        __builtin_amdgcn_readlane(__builtin_bit_cast(int, v), l));
}

// ---- prep: W split into B-frag layout (b<60) + rowsums (b>=60) ----
__global__ __launch_bounds__(256)
void prep_basic(const float* __restrict__ s_feats, const float* __restrict__ W,
                float* __restrict__ rs, short* __restrict__ whi, short* __restrict__ wlo)
{
    int b = blockIdx.x;
    if (b < 60) {
        int wv = threadIdx.x >> 6, lane = threadIdx.x & 63;
        int id = b * 4 + wv;
        int t = id / KBT, kb = id % KBT;
        short8 hi8, lo8;
        #pragma unroll
        for (int j = 0; j < 8; ++j) {
            int row = kb * 32 + ((lane >> 4) & 3) * 8 + j;
            int col = t * 16 + (lane & 15);
            float x = W[(size_t)row * COUT + col];
            short h = f32_bf16(x);
            hi8[j] = h;
            lo8[j] = f32_bf16(x - bf16_f32(h));
        }
        ((short8*)whi)[id * 64 + lane] = hi8;
        ((short8*)wlo)[id * 64 + lane] = lo8;
    } else {
        int tdx = (b - 60) * 256 + threadIdx.x;
        int row = tdx >> 3, l8 = tdx & 7;
        if (row < MS) {
            const float4* p = (const float4*)(s_feats + (size_t)row * CIN + l8 * 8);
            float4 a = p[0], c = p[1];
            float s = ((a.x + a.y) + (a.z + a.w)) + ((c.x + c.y) + (c.z + c.w));
            s += __shfl_xor(s, 1);
            s += __shfl_xor(s, 2);
            s += __shfl_xor(s, 4);
            if (l8 == 0) rs[row] = s;
        }
    }
}

// ---- main fused kernel ----
__global__ __launch_bounds__(512, 4)
void kpconv_mfma(const float* __restrict__ q_pts,
                 const float* __restrict__ s_pts,
                 const float* __restrict__ s_feats,
                 const int*   __restrict__ neigh,
                 const float* __restrict__ kpts,
                 const float* __restrict__ rowsum,
                 const short* __restrict__ whi,
                 const short* __restrict__ wlo,
                 float*       __restrict__ out)
{
    __shared__ __align__(16) unsigned int smem[QB * ASTR];   // 41472 B union
    __shared__ float norm_s[QB];

    float* smf = (float*)smem;
    const int tid  = threadIdx.x;
    const int lane = tid & 63;
    const int wv   = tid >> 6;       // 0..7
    const int blk  = blockIdx.x;
    const int k32  = lane & 31;
    const int half = lane >> 5;
    const int quad = lane >> 4;
    const int c15  = lane & 15;

    int*   cpk  = (int*)(smf + OF_CPK) + wv * 32;
    int*   cem  = (int*)(smf + OF_CEM) + wv * 32;
    float* kp_s = smf + OF_KP;

    if (tid < KP * 3) kp_s[tid] = kpts[tid];
    __syncthreads();

    float kfv[4][KP];   // scalar accumulators (AGPR-friendly; do NOT vectorize)

    // ---------------- Phase 1: wave-per-query aggregation ----------------
    #pragma unroll
    for (int j = 0; j < 4; ++j) {
        const int q  = wv * 4 + j;
        const int n  = blk * QB + q;
        const int nc = n < NQ ? n : NQ - 1;
        const float qx = q_pts[nc * 3 + 0];
        const float qy = q_pts[nc * 3 + 1];
        const float qz = q_pts[nc * 3 + 2];

        // 1a: per-lane (halves redundant) index, delta, count flag
        int  idxv  = neigh[nc * KNN + k32];
        bool valid = idxv < MS;
        int  icv   = valid ? idxv : MS - 1;
        float px = s_pts[icv * 3 + 0];
        float py = s_pts[icv * 3 + 1];
        float pz = s_pts[icv * 3 + 2];
        float dx = valid ? px - qx : 1e6f;
        float dy = valid ? py - qy : 1e6f;
        float dz = valid ? pz - qz : 1e6f;
        bool flag = valid && (rowsum[icv] > 0.0f);
        {
            unsigned long long b = __ballot(flag);      // halves duplicate each k
            int cnt = (int)(__popcll(b) >> 1);
            if (lane == 0) norm_s[q] = 1.0f / (float)(cnt > 1 ? cnt : 1);
        }

        // 1b: h[k][e] in registers; lane (k32,half) holds e = 2p+half in hreg[p].
        // Also build this lane's e-bits: bit (2p+half) set iff hreg[p] > 0.
        float hreg[8];
        unsigned ebits = 0;
        #pragma unroll
        for (int p = 0; p < 8; ++p) {
            const int e = (p << 1) + half;
            float hh = 0.0f;
            if (e < KP) {
                float ax = dx - kp_s[e * 3 + 0];
                float ay = dy - kp_s[e * 3 + 1];
                float az = dz - kp_s[e * 3 + 2];
                float d2 = ax * ax + ay * ay + az * az + 1e-8f;
                hh = 1.0f - sqrtf(d2) * KP_EXT_INV;
                hh = hh > 0.0f ? hh : 0.0f;
                if (hh > 0.0f) ebits |= (1u << e);
            }
            hreg[p] = hh;
        }
        // full 15-bit e-mask for row k32 (combine even/odd halves)
        unsigned em = ebits | (unsigned)__shfl_xor((int)ebits, 32);
        unsigned int kmask = (unsigned int)__ballot(em != 0);  // low 32 = per-k live
        const int nv = __popc(kmask);

        // compaction: slot -> (row<<6)|k and its e-mask; pads -> 0 (em=0 skips all)
        if (lane < KNN) {
            bool bit = (kmask >> k32) & 1u;
            unsigned lm = (1u << k32) - 1u;
            int pos = bit ? __popc(kmask & lm) : nv + __popc((~kmask) & lm);
            cpk[pos] = bit ? ((idxv << 6) | k32) : 0;
            cem[pos] = bit ? (int)em : 0;
        }
        __builtin_amdgcn_wave_barrier();

        #pragma unroll
        for (int e = 0; e < KP; ++e) kfv[j][e] = 0.0f;

        const int nvr = (nv + 3) & ~3;
        for (int base = 0; base < nvr; base += 4) {
            int pk[4], em4[4];
            float nf[4];
            #pragma unroll
            for (int u = 0; u < 4; ++u) {
                pk[u]  = __builtin_amdgcn_readfirstlane(cpk[base + u]);
                em4[u] = __builtin_amdgcn_readfirstlane(cem[base + u]);
            }
            #pragma unroll
            for (int u = 0; u < 4; ++u) nf[u] = s_feats[(size_t)(pk[u] >> 6) * CIN + lane];
            #pragma unroll
            for (int u = 0; u < 4; ++u) {
                const int kk = pk[u] & 31;      // scalar
                const int emu = em4[u];         // scalar -> uniform branches below
                const float f = nf[u];
                #pragma unroll
                for (int e = 0; e < KP; ++e) {
                    if (emu & (1 << e)) {       // wave-uniform s_cbranch
                        float he = readlane_f(hreg[e >> 1], kk | ((e & 1) << 5));
                        kfv[j][e] += he * f;
                    }
                }
            }
        }
    }

    // ---------------- Phase 2: split-bf16 MFMA GEMM (R4-verified) ----------------
    const short8* wh = (const short8*)whi;
    const short8* wl = (const short8*)wlo;
    f32x4 acc0 = {0.f, 0.f, 0.f, 0.f};   // m-tile 0 (queries 0..15)
    f32x4 acc1 = {0.f, 0.f, 0.f, 0.f};   // m-tile 1 (queries 16..31)
    const int qA = c15;

    #pragma unroll
    for (int r = 0; r < RND; ++r) {
        __syncthreads();
        #pragma unroll
        for (int j = 0; j < 4; ++j) {
            const int qrow = (4 * wv + j) * ASTR;
            #pragma unroll
            for (int e5 = 0; e5 < RE; ++e5) {
                smem[qrow + e5 * CIN + lane] = pack_hilo(kfv[j][r * RE + e5]);
            }
        }
        __syncthreads();

        #pragma unroll 2
        for (int kb = 0; kb < KBR; ++kb) {
            const uint4* a0p = (const uint4*)(smem + qA * ASTR + kb * 32 + quad * 8);
            uint4 a0 = a0p[0], a0b = a0p[1];
            const uint4* a1p = (const uint4*)(smem + (16 + qA) * ASTR + kb * 32 + quad * 8);
            uint4 a1 = a1p[0], a1b = a1p[1];
            short8 ah0, al0, ah1, al1;
            unpack8(a0, a0b, ah0, al0);
            unpack8(a1, a1b, ah1, al1);

            const int kbg = r * KBR + kb;
            short8 bh = wh[(wv * KBT + kbg) * 64 + lane];
            short8 bl = wl[(wv * KBT + kbg) * 64 + lane];

            acc0 = __builtin_amdgcn_mfma_f32_16x16x32_bf16(ah0, bh, acc0, 0, 0, 0);
            acc1 = __builtin_amdgcn_mfma_f32_16x16x32_bf16(ah1, bh, acc1, 0, 0, 0);
            acc0 = __builtin_amdgcn_mfma_f32_16x16x32_bf16(ah0, bl, acc0, 0, 0, 0);
            acc1 = __builtin_amdgcn_mfma_f32_16x16x32_bf16(ah1, bl, acc1, 0, 0, 0);
            acc0 = __builtin_amdgcn_mfma_f32_16x16x32_bf16(al0, bh, acc0, 0, 0, 0);
            acc1 = __builtin_amdgcn_mfma_f32_16x16x32_bf16(al1, bh, acc1, 0, 0, 0);
        }
    }

    // epilogue: D row m = quad*4+rr (query within tile), col = lane&15
    const int oc = c15;
    #pragma unroll
    for (int rr = 0; rr < 4; ++rr) {
        int qm0 = quad * 4 + rr;
        int qm1 = 16 + qm0;
        int n0 = blk * QB + qm0;
        int n1 = blk * QB + qm1;
        if (n0 < NQ) out[(size_t)n0 * COUT + wv * 16 + oc] = acc0[rr] * norm_s[qm0];
        if (n1 < NQ) out[(size_t)n1 * COUT + wv * 16 + oc] = acc1[rr] * norm_s[qm1];
    }
}

// ---- fallback (no workspace; R2-verified structure) ----
__global__ __launch_bounds__(256, 6)
void kpconv_fallback(const float* __restrict__ q_pts,
                     const float* __restrict__ s_pts,
                     const float* __restrict__ s_feats,
                     const int*   __restrict__ neigh,
                     const float* __restrict__ W,
                     const float* __restrict__ kpts,
                     float*       __restrict__ out)
{
    constexpr int QBF = 16, CHUNK_I = 320, NPAIR = 160;
    __shared__ __align__(16) float smem[NPAIR * 32];
    __shared__ float norm_s[QBF];
    float (*h_lds)[KNN][20] = (float (*)[KNN][20])smem;
    float (*dxyz)[KNN][3]   = (float (*)[KNN][3])(smem + 2560);
    int*   idxl             = (int*)(smem + 2944);
    float* kp_s             = smem + 3072;

    const int tid = threadIdx.x, lane = tid & 63, wv = tid >> 6, blk = blockIdx.x;
    const int k32 = lane & 31, half = lane >> 5;
    if (tid < KP * 3) kp_s[tid] = kpts[tid];
    __syncthreads();
    float kfv[4][KP];

    #pragma unroll
    for (int j = 0; j < 4; ++j) {
        const int q = wv * 4 + j, n = blk * QBF + q;
        const float qx = q_pts[n*3], qy = q_pts[n*3+1], qz = q_pts[n*3+2];
        if (lane < KNN) {
            int idx = neigh[n * KNN + k32];
            idxl[wv * KNN + k32] = idx;
            bool valid = idx < MS;
            int ic = valid ? idx : MS - 1;
            dxyz[wv][k32][0] = valid ? s_pts[ic*3]   - qx : 1e6f;
            dxyz[wv][k32][1] = valid ? s_pts[ic*3+1] - qy : 1e6f;
            dxyz[wv][k32][2] = valid ? s_pts[ic*3+2] - qz : 1e6f;
        }
        __builtin_amdgcn_wave_barrier();
        const float dx = dxyz[wv][k32][0], dy = dxyz[wv][k32][1], dz = dxyz[wv][k32][2];
        float om = 0.0f;
        #pragma unroll
        for (int p = 0; p < 8; ++p) {
            const int e = (p << 1) + half;
            if (e < KP) {
                float ax = dx - kp_s[e*3], ay = dy - kp_s[e*3+1], az = dz - kp_s[e*3+2];
                float hh = 1.0f - sqrtf(ax*ax + ay*ay + az*az + 1e-8f) * KP_EXT_INV;
                hh = hh > 0.0f ? hh : 0.0f;
                h_lds[wv][k32][e] = hh;
                om = fmaxf(om, hh);
            }
        }
        om = fmaxf(om, __shfl_xor(om, 32));
        unsigned int kmask = (unsigned int)__ballot(om > 0.0f);
        __builtin_amdgcn_wave_barrier();
        {
            int idx = idxl[wv * KNN + k32];
            bool valid = idx < MS;
            int ic = valid ? idx : MS - 1;
            const float4* rp = (const float4*)(s_feats + (size_t)ic * CIN + half * 32);
            float4 s4 = rp[0];
            #pragma unroll
            for (int t = 1; t < 8; ++t) { float4 a = rp[t]; s4.x+=a.x; s4.y+=a.y; s4.z+=a.z; s4.w+=a.w; }
            float s = (s4.x + s4.y) + (s4.z + s4.w);
            s += __shfl_xor(s, 32);
            unsigned long long b = __ballot(valid && (s > 0.0f));
            int cnt = (int)(__popcll(b) >> 1);
            if (lane == 0) norm_s[q] = 1.0f / (float)(cnt > 1 ? cnt : 1);
        }
        #pragma unroll
        for (int e = 0; e < KP; ++e) kfv[j][e] = 0.0f;
        unsigned int mk = kmask;
        while (mk) {
            int k = __builtin_ctz(mk); mk &= mk - 1;
            int idx2 = idxl[wv * KNN + k];
            int ic2 = idx2 < MS ? idx2 : MS - 1;
            float nf = s_feats[(size_t)ic2 * CIN + lane];
            const float4* hr = (const float4*)(&h_lds[wv][k][0]);
            float4 h0 = hr[0], h1 = hr[1], h2 = hr[2], h3 = hr[3];
            kfv[j][0]+=h0.x*nf; kfv[j][1]+=h0.y*nf; kfv[j][2]+=h0.z*nf; kfv[j][3]+=h0.w*nf;
            kfv[j][4]+=h1.x*nf; kfv[j][5]+=h1.y*nf; kfv[j][6]+=h1.z*nf; kfv[j][7]+=h1.w*nf;
            kfv[j][8]+=h2.x*nf; kfv[j][9]+=h2.y*nf; kfv[j][10]+=h2.z*nf; kfv[j][11]+=h2.w*nf;
            kfv[j][12]+=h3.x*nf; kfv[j][13]+=h3.y*nf; kfv[j][14]+=h3.z*nf;
        }
    }

    const int o4 = tid & 31, qi = tid >> 5, q0 = qi * 2, q1 = q0 + 1;
    float4 tot0 = make_float4(0,0,0,0), tot1 = make_float4(0,0,0,0);
    #pragma unroll
    for (int r = 0; r < 3; ++r) {
        __syncthreads();
        #pragma unroll
        for (int j = 0; j < 4; ++j) {
            const int q = wv * 4 + j;
            #pragma unroll
            for (int e5 = 0; e5 < 5; ++e5) {
                int i = e5 * CIN + lane, pr = i >> 1, m = pr & 14;
                smem[pr * 32 + ((q ^ m) << 1) + (i & 1)] = kfv[j][r * 5 + e5];
            }
        }
        __syncthreads();
        const float* wb = W + (size_t)(r * CHUNK_I) * COUT + (o4 << 2);
        float4 acc0 = make_float4(0,0,0,0), acc1 = make_float4(0,0,0,0);
        #pragma unroll 4
        for (int p = 0; p < NPAIR; ++p) {
            float4 kk = *(const float4*)(smem + p * 32 + ((q0 ^ (p & 14)) << 1));
            float4 w0 = *(const float4*)(wb + (size_t)(2*p) * COUT);
            float4 w1 = *(const float4*)(wb + (size_t)(2*p+1) * COUT);
            acc0.x+=w0.x*kk.x; acc0.y+=w0.y*kk.x; acc0.z+=w0.z*kk.x; acc0.w+=w0.w*kk.x;
            acc1.x+=w0.x*kk.z; acc1.y+=w0.y*kk.z; acc1.z+=w0.z*kk.z; acc1.w+=w0.w*kk.z;
            acc0.x+=w1.x*kk.y; acc0.y+=w1.y*kk.y; acc0.z+=w1.z*kk.y; acc0.w+=w1.w*kk.y;
            acc1.x+=w1.x*kk.w; acc1.y+=w1.y*kk.w; acc1.z+=w1.z*kk.w; acc1.w+=w1.w*kk.w;
        }
        tot0.x+=acc0.x; tot0.y+=acc0.y; tot0.z+=acc0.z; tot0.w+=acc0.w;
        tot1.x+=acc1.x; tot1.y+=acc1.y; tot1.z+=acc1.z; tot1.w+=acc1.w;
    }
    const float nm0 = norm_s[q0], nm1 = norm_s[q1];
    const size_t base = (size_t)(blk * QBF) * COUT + (o4 << 2);
    *(float4*)(out + base + (size_t)q0 * COUT) =
        make_float4(tot0.x*nm0, tot0.y*nm0, tot0.z*nm0, tot0.w*nm0);
    *(float4*)(out + base + (size_t)q1 * COUT) =
        make_float4(tot1.x*nm1, tot1.y*nm1, tot1.z*nm1, tot1.w*nm1);
}

extern "C" void kernel_launch(void* const* d_in, const int* in_sizes, int n_in,
                              void* d_out, int out_size, void* d_ws, size_t ws_size,
                              hipStream_t stream) {
    const float* q_pts   = (const float*)d_in[0];
    const float* s_pts   = (const float*)d_in[1];
    const float* s_feats = (const float*)d_in[2];
    const int*   neigh   = (const int*)d_in[3];
    const float* W       = (const float*)d_in[4];
    const float* kpts    = (const float*)d_in[5];
    float* outp = (float*)d_out;

    dim3 mgrid((NQ + QB - 1) / QB);   // 1563
    dim3 mblock(512);

    if (ws_size >= WSB_END) {
        float* rs  = (float*)d_ws;
        short* whi = (short*)((char*)d_ws + WSB_HI);
        short* wlo = (short*)((char*)d_ws + WSB_LO);
        int rs_blocks = (MS * 8 + 255) / 256;
        hipLaunchKernelGGL(prep_basic, dim3(60 + rs_blocks), dim3(256), 0, stream,
                           s_feats, W, rs, whi, wlo);
        hipLaunchKernelGGL(kpconv_mfma, mgrid, mblock, 0, stream,
                           q_pts, s_pts, s_feats, neigh, kpts, rs, whi, wlo, outp);
    } else {
        hipLaunchKernelGGL(kpconv_fallback, dim3(NQ / 16), dim3(256), 0, stream,
                           q_pts, s_pts, s_feats, neigh, W, kpts, outp);
    }
}

// Round 10
// 156.011 us; speedup vs baseline: 1.0142x; 1.0142x over previous
//
#include <hip/hip_runtime.h>

// KPConv fused, R10 = R8 skeleton (87us verified) + latency & VALU cuts:
//  - prologue hoists all 4 queries' 1a gathers (neigh/s_pts/rowsum) -> 16+ loads
//    in flight at once; ballots + norm_s computed there.
//  - slot loop: 2-deep software pipeline (prefetch next batch-4 pk/nf before
//    consuming current), R8's spill-free granularity, in-bounds clamped.
//  - phase 2: kf stored as SEPARATE bf16 hi/lo LDS planes (row stride 328 shorts
//    = 656 B, 16B-aligned, 2-way-free banks) -> A-frag = direct ds_read_b128,
//    deletes all ~480 v_perm per wave. R9's e-mask guard removed (measured neutral).
//  - accumulators stay scalar float kfv[4][15] (AGPR-friendly; R6 lesson).

namespace {
constexpr int NQ   = 50000;
constexpr int MS   = 50000;
constexpr int KNN  = 32;
constexpr int KP   = 15;
constexpr int CIN  = 64;
constexpr int COUT = 128;
constexpr int QB   = 32;                 // queries per block (2 MFMA m-tiles)
constexpr int ROWS = KP * CIN;           // 960
constexpr int RND  = 3;
constexpr int RE   = 5;                  // kernel points per round
constexpr int KBR  = (RE * CIN) / 32;    // 10
constexpr int KBT  = ROWS / 32;          // 30
constexpr int SRH  = 328;                // kf row stride in shorts (656 B = 41*16)
constexpr int LO_OFF = QB * SRH;         // 10496 shorts -> lo plane offset
constexpr float KP_EXT_INV = 1.0f / 1.2f;
constexpr int OF_CPK = 0;                // 8 waves * 32 ints (overlaps kf rows; dead by dump)
constexpr int OF_KP  = 256;              // 45 floats
constexpr size_t WSB_HI  = 200704;
constexpr size_t WSB_LO  = 446464;
constexpr size_t WSB_END = 692224;
}

typedef __attribute__((ext_vector_type(8))) short short8;
typedef __attribute__((ext_vector_type(4))) float f32x4;

__device__ __forceinline__ short f32_bf16(float x) {
    unsigned u = __builtin_bit_cast(unsigned, x);
    u = u + 0x7fffu + ((u >> 16) & 1u);
    return (short)(u >> 16);
}
__device__ __forceinline__ float bf16_f32(short h) {
    unsigned u = ((unsigned)(unsigned short)h) << 16;
    return __builtin_bit_cast(float, u);
}
__device__ __forceinline__ float readlane_f(float v, int l) {
    return __builtin_bit_cast(float,
        __builtin_amdgcn_readlane(__builtin_bit_cast(int, v), l));
}

// ---- prep: W split into B-frag layout (b<60) + rowsums (b>=60) ----
__global__ __launch_bounds__(256)
void prep_basic(const float* __restrict__ s_feats, const float* __restrict__ W,
                float* __restrict__ rs, short* __restrict__ whi, short* __restrict__ wlo)
{
    int b = blockIdx.x;
    if (b < 60) {
        int wv = threadIdx.x >> 6, lane = threadIdx.x & 63;
        int id = b * 4 + wv;
        int t = id / KBT, kb = id % KBT;
        short8 hi8, lo8;
        #pragma unroll
        for (int j = 0; j < 8; ++j) {
            int row = kb * 32 + ((lane >> 4) & 3) * 8 + j;
            int col = t * 16 + (lane & 15);
            float x = W[(size_t)row * COUT + col];
            short h = f32_bf16(x);
            hi8[j] = h;
            lo8[j] = f32_bf16(x - bf16_f32(h));
        }
        ((short8*)whi)[id * 64 + lane] = hi8;
        ((short8*)wlo)[id * 64 + lane] = lo8;
    } else {
        int tdx = (b - 60) * 256 + threadIdx.x;
        int row = tdx >> 3, l8 = tdx & 7;
        if (row < MS) {
            const float4* p = (const float4*)(s_feats + (size_t)row * CIN + l8 * 8);
            float4 a = p[0], c = p[1];
            float s = ((a.x + a.y) + (a.z + a.w)) + ((c.x + c.y) + (c.z + c.w));
            s += __shfl_xor(s, 1);
            s += __shfl_xor(s, 2);
            s += __shfl_xor(s, 4);
            if (l8 == 0) rs[row] = s;
        }
    }
}

// ---- main fused kernel ----
__global__ __launch_bounds__(512, 4)
void kpconv_mfma(const float* __restrict__ q_pts,
                 const float* __restrict__ s_pts,
                 const float* __restrict__ s_feats,
                 const int*   __restrict__ neigh,
                 const float* __restrict__ kpts,
                 const float* __restrict__ rowsum,
                 const short* __restrict__ whi,
                 const short* __restrict__ wlo,
                 float*       __restrict__ out)
{
    __shared__ __align__(16) short smem_s[2 * QB * SRH];   // 41984 B (hi plane + lo plane)
    __shared__ float norm_s[QB];

    float* smf = (float*)smem_s;
    const int tid  = threadIdx.x;
    const int lane = tid & 63;
    const int wv   = tid >> 6;       // 0..7
    const int blk  = blockIdx.x;
    const int k32  = lane & 31;
    const int quad = lane >> 4;
    const int half = lane >> 5;
    const int c15  = lane & 15;

    int*   cpk  = (int*)(smf + OF_CPK) + wv * 32;   // overlaps kf rows; dead before dump
    float* kp_s = smf + OF_KP;

    if (tid < KP * 3) kp_s[tid] = kpts[tid];
    __syncthreads();

    float kfv[4][KP];   // scalar accumulators (AGPR-friendly; do NOT vectorize)

    // ---------------- Phase 1 prologue: all 4 queries' gathers in flight ----------------
    float dxa[4], dya[4], dza[4];
    int   idxa[4];
    {
        int nca[4];
        #pragma unroll
        for (int j = 0; j < 4; ++j) {
            const int n = blk * QB + wv * 4 + j;
            nca[j] = n < NQ ? n : NQ - 1;
        }
        #pragma unroll
        for (int j = 0; j < 4; ++j) idxa[j] = neigh[nca[j] * KNN + k32];
        #pragma unroll
        for (int j = 0; j < 4; ++j) {
            const float qx = q_pts[nca[j] * 3 + 0];
            const float qy = q_pts[nca[j] * 3 + 1];
            const float qz = q_pts[nca[j] * 3 + 2];
            bool valid = idxa[j] < MS;
            int  icv   = valid ? idxa[j] : MS - 1;
            float px = s_pts[icv * 3 + 0];
            float py = s_pts[icv * 3 + 1];
            float pz = s_pts[icv * 3 + 2];
            float rsv = rowsum[icv];
            dxa[j] = valid ? px - qx : 1e6f;
            dya[j] = valid ? py - qy : 1e6f;
            dza[j] = valid ? pz - qz : 1e6f;
            bool flag = valid && (rsv > 0.0f);
            unsigned long long b = __ballot(flag);      // halves duplicate each k
            int cnt = (int)(__popcll(b) >> 1);
            if (lane == 0) norm_s[wv * 4 + j] = 1.0f / (float)(cnt > 1 ? cnt : 1);
        }
    }

    // ---------------- Phase 1 main: per-query h + aggregation ----------------
    #pragma unroll
    for (int j = 0; j < 4; ++j) {
        const float dx = dxa[j], dy = dya[j], dz = dza[j];
        const int idxv = idxa[j];

        // 1b: h[k][e] in registers; lane (k32,half) holds e = 2p+half in hreg[p]
        float hreg[8];
        float om = 0.0f;
        #pragma unroll
        for (int p = 0; p < 8; ++p) {
            const int e = (p << 1) + half;
            float hh = 0.0f;
            if (e < KP) {
                float ax = dx - kp_s[e * 3 + 0];
                float ay = dy - kp_s[e * 3 + 1];
                float az = dz - kp_s[e * 3 + 2];
                float d2 = ax * ax + ay * ay + az * az + 1e-8f;
                hh = 1.0f - sqrtf(d2) * KP_EXT_INV;
                hh = hh > 0.0f ? hh : 0.0f;
            }
            hreg[p] = hh;
            om = fmaxf(om, hh);
        }
        om = fmaxf(om, __shfl_xor(om, 32));
        unsigned int kmask = (unsigned int)__ballot(om > 0.0f);  // low 32 = per-k live
        const int nv = __popc(kmask);

        // compaction: slot -> (row<<6)|k for live, 0 for pads
        if (lane < KNN) {
            bool bit = (kmask >> k32) & 1u;
            unsigned lm = (1u << k32) - 1u;
            int pos = bit ? __popc(kmask & lm) : nv + __popc((~kmask) & lm);
            cpk[pos] = bit ? ((idxv << 6) | k32) : 0;
        }
        __builtin_amdgcn_wave_barrier();

        #pragma unroll
        for (int e = 0; e < KP; ++e) kfv[j][e] = 0.0f;

        // 2-deep pipelined batch-4 slot loop (R8 granularity, prefetch next)
        const int nvr = (nv + 3) & ~3;
        int   pkc[4];
        float nfc[4];
        #pragma unroll
        for (int u = 0; u < 4; ++u) pkc[u] = __builtin_amdgcn_readfirstlane(cpk[u]);
        #pragma unroll
        for (int u = 0; u < 4; ++u) nfc[u] = s_feats[(size_t)(pkc[u] >> 6) * CIN + lane];

        for (int base = 0; base < nvr; base += 4) {
            int   pkn[4];
            float nfn[4];
            #pragma unroll
            for (int u = 0; u < 4; ++u) {
                int ii = base + 4 + u;
                ii = ii < 31 ? ii : 31;          // in-bounds; pads hold 0 (safe)
                pkn[u] = __builtin_amdgcn_readfirstlane(cpk[ii]);
            }
            #pragma unroll
            for (int u = 0; u < 4; ++u) nfn[u] = s_feats[(size_t)(pkn[u] >> 6) * CIN + lane];

            #pragma unroll
            for (int u = 0; u < 4; ++u) {
                const float f = (base + u < nv) ? nfc[u] : 0.0f;
                const int   kk = pkc[u] & 63;
                #pragma unroll
                for (int e = 0; e < KP; ++e) {
                    float he = readlane_f(hreg[e >> 1], kk | ((e & 1) << 5));
                    kfv[j][e] += he * f;
                }
            }
            #pragma unroll
            for (int u = 0; u < 4; ++u) { pkc[u] = pkn[u]; nfc[u] = nfn[u]; }
        }
    }

    // ---------------- Phase 2: split-bf16 MFMA GEMM, hi/lo LDS planes ----------------
    const short8* wh = (const short8*)whi;
    const short8* wl = (const short8*)wlo;
    f32x4 acc0 = {0.f, 0.f, 0.f, 0.f};   // m-tile 0 (queries 0..15)
    f32x4 acc1 = {0.f, 0.f, 0.f, 0.f};   // m-tile 1 (queries 16..31)
    const int qA = c15;

    #pragma unroll
    for (int r = 0; r < RND; ++r) {
        __syncthreads();
        // dump: row q, element i = e5*64 + lane; hi plane + lo plane (ds_write_b16)
        #pragma unroll
        for (int j = 0; j < 4; ++j) {
            const int q = 4 * wv + j;
            #pragma unroll
            for (int e5 = 0; e5 < RE; ++e5) {
                float v  = kfv[j][r * RE + e5];
                short hi = f32_bf16(v);
                short lo = f32_bf16(v - bf16_f32(hi));
                smem_s[q * SRH + e5 * 64 + lane]          = hi;
                smem_s[LO_OFF + q * SRH + e5 * 64 + lane] = lo;
            }
        }
        __syncthreads();

        #pragma unroll 2
        for (int kb = 0; kb < KBR; ++kb) {
            const int ai = kb * 32 + quad * 8;
            short8 ah0 = *(const short8*)(smem_s + qA * SRH + ai);
            short8 al0 = *(const short8*)(smem_s + LO_OFF + qA * SRH + ai);
            short8 ah1 = *(const short8*)(smem_s + (16 + qA) * SRH + ai);
            short8 al1 = *(const short8*)(smem_s + LO_OFF + (16 + qA) * SRH + ai);

            const int kbg = r * KBR + kb;
            short8 bh = wh[(wv * KBT + kbg) * 64 + lane];
            short8 bl = wl[(wv * KBT + kbg) * 64 + lane];

            acc0 = __builtin_amdgcn_mfma_f32_16x16x32_bf16(ah0, bh, acc0, 0, 0, 0);
            acc1 = __builtin_amdgcn_mfma_f32_16x16x32_bf16(ah1, bh, acc1, 0, 0, 0);
            acc0 = __builtin_amdgcn_mfma_f32_16x16x32_bf16(ah0, bl, acc0, 0, 0, 0);
            acc1 = __builtin_amdgcn_mfma_f32_16x16x32_bf16(ah1, bl, acc1, 0, 0, 0);
            acc0 = __builtin_amdgcn_mfma_f32_16x16x32_bf16(al0, bh, acc0, 0, 0, 0);
            acc1 = __builtin_amdgcn_mfma_f32_16x16x32_bf16(al1, bh, acc1, 0, 0, 0);
        }
    }

    // epilogue: D row m = quad*4+rr (query within tile), col = lane&15
    const int oc = c15;
    #pragma unroll
    for (int rr = 0; rr < 4; ++rr) {
        int qm0 = quad * 4 + rr;
        int qm1 = 16 + qm0;
        int n0 = blk * QB + qm0;
        int n1 = blk * QB + qm1;
        if (n0 < NQ) out[(size_t)n0 * COUT + wv * 16 + oc] = acc0[rr] * norm_s[qm0];
        if (n1 < NQ) out[(size_t)n1 * COUT + wv * 16 + oc] = acc1[rr] * norm_s[qm1];
    }
}

// ---- fallback (no workspace; R2-verified structure) ----
__global__ __launch_bounds__(256, 6)
void kpconv_fallback(const float* __restrict__ q_pts,
                     const float* __restrict__ s_pts,
                     const float* __restrict__ s_feats,
                     const int*   __restrict__ neigh,
                     const float* __restrict__ W,
                     const float* __restrict__ kpts,
                     float*       __restrict__ out)
{
    constexpr int QBF = 16, CHUNK_I = 320, NPAIR = 160;
    __shared__ __align__(16) float smem[NPAIR * 32];
    __shared__ float norm_s[QBF];
    float (*h_lds)[KNN][20] = (float (*)[KNN][20])smem;
    float (*dxyz)[KNN][3]   = (float (*)[KNN][3])(smem + 2560);
    int*   idxl             = (int*)(smem + 2944);
    float* kp_s             = smem + 3072;

    const int tid = threadIdx.x, lane = tid & 63, wv = tid >> 6, blk = blockIdx.x;
    const int k32 = lane & 31, half = lane >> 5;
    if (tid < KP * 3) kp_s[tid] = kpts[tid];
    __syncthreads();
    float kfv[4][KP];

    #pragma unroll
    for (int j = 0; j < 4; ++j) {
        const int q = wv * 4 + j, n = blk * QBF + q;
        const float qx = q_pts[n*3], qy = q_pts[n*3+1], qz = q_pts[n*3+2];
        if (lane < KNN) {
            int idx = neigh[n * KNN + k32];
            idxl[wv * KNN + k32] = idx;
            bool valid = idx < MS;
            int ic = valid ? idx : MS - 1;
            dxyz[wv][k32][0] = valid ? s_pts[ic*3]   - qx : 1e6f;
            dxyz[wv][k32][1] = valid ? s_pts[ic*3+1] - qy : 1e6f;
            dxyz[wv][k32][2] = valid ? s_pts[ic*3+2] - qz : 1e6f;
        }
        __builtin_amdgcn_wave_barrier();
        const float dx = dxyz[wv][k32][0], dy = dxyz[wv][k32][1], dz = dxyz[wv][k32][2];
        float om = 0.0f;
        #pragma unroll
        for (int p = 0; p < 8; ++p) {
            const int e = (p << 1) + half;
            if (e < KP) {
                float ax = dx - kp_s[e*3], ay = dy - kp_s[e*3+1], az = dz - kp_s[e*3+2];
                float hh = 1.0f - sqrtf(ax*ax + ay*ay + az*az + 1e-8f) * KP_EXT_INV;
                hh = hh > 0.0f ? hh : 0.0f;
                h_lds[wv][k32][e] = hh;
                om = fmaxf(om, hh);
            }
        }
        om = fmaxf(om, __shfl_xor(om, 32));
        unsigned int kmask = (unsigned int)__ballot(om > 0.0f);
        __builtin_amdgcn_wave_barrier();
        {
            int idx = idxl[wv * KNN + k32];
            bool valid = idx < MS;
            int ic = valid ? idx : MS - 1;
            const float4* rp = (const float4*)(s_feats + (size_t)ic * CIN + half * 32);
            float4 s4 = rp[0];
            #pragma unroll
            for (int t = 1; t < 8; ++t) { float4 a = rp[t]; s4.x+=a.x; s4.y+=a.y; s4.z+=a.z; s4.w+=a.w; }
            float s = (s4.x + s4.y) + (s4.z + s4.w);
            s += __shfl_xor(s, 32);
            unsigned long long b = __ballot(valid && (s > 0.0f));
            int cnt = (int)(__popcll(b) >> 1);
            if (lane == 0) norm_s[q] = 1.0f / (float)(cnt > 1 ? cnt : 1);
        }
        #pragma unroll
        for (int e = 0; e < KP; ++e) kfv[j][e] = 0.0f;
        unsigned int mk = kmask;
        while (mk) {
            int k = __builtin_ctz(mk); mk &= mk - 1;
            int idx2 = idxl[wv * KNN + k];
            int ic2 = idx2 < MS ? idx2 : MS - 1;
            float nf = s_feats[(size_t)ic2 * CIN + lane];
            const float4* hr = (const float4*)(&h_lds[wv][k][0]);
            float4 h0 = hr[0], h1 = hr[1], h2 = hr[2], h3 = hr[3];
            kfv[j][0]+=h0.x*nf; kfv[j][1]+=h0.y*nf; kfv[j][2]+=h0.z*nf; kfv[j][3]+=h0.w*nf;
            kfv[j][4]+=h1.x*nf; kfv[j][5]+=h1.y*nf; kfv[j][6]+=h1.z*nf; kfv[j][7]+=h1.w*nf;
            kfv[j][8]+=h2.x*nf; kfv[j][9]+=h2.y*nf; kfv[j][10]+=h2.z*nf; kfv[j][11]+=h2.w*nf;
            kfv[j][12]+=h3.x*nf; kfv[j][13]+=h3.y*nf; kfv[j][14]+=h3.z*nf;
        }
    }

    const int o4 = tid & 31, qi = tid >> 5, q0 = qi * 2, q1 = q0 + 1;
    float4 tot0 = make_float4(0,0,0,0), tot1 = make_float4(0,0,0,0);
    #pragma unroll
    for (int r = 0; r < 3; ++r) {
        __syncthreads();
        #pragma unroll
        for (int j = 0; j < 4; ++j) {
            const int q = wv * 4 + j;
            #pragma unroll
            for (int e5 = 0; e5 < 5; ++e5) {
                int i = e5 * CIN + lane, pr = i >> 1, m = pr & 14;
                smem[pr * 32 + ((q ^ m) << 1) + (i & 1)] = kfv[j][r * 5 + e5];
            }
        }
        __syncthreads();
        const float* wb = W + (size_t)(r * CHUNK_I) * COUT + (o4 << 2);
        float4 acc0 = make_float4(0,0,0,0), acc1 = make_float4(0,0,0,0);
        #pragma unroll 4
        for (int p = 0; p < NPAIR; ++p) {
            float4 kk = *(const float4*)(smem + p * 32 + ((q0 ^ (p & 14)) << 1));
            float4 w0 = *(const float4*)(wb + (size_t)(2*p) * COUT);
            float4 w1 = *(const float4*)(wb + (size_t)(2*p+1) * COUT);
            acc0.x+=w0.x*kk.x; acc0.y+=w0.y*kk.x; acc0.z+=w0.z*kk.x; acc0.w+=w0.w*kk.x;
            acc1.x+=w0.x*kk.z; acc1.y+=w0.y*kk.z; acc1.z+=w0.z*kk.z; acc1.w+=w0.w*kk.z;
            acc0.x+=w1.x*kk.y; acc0.y+=w1.y*kk.y; acc0.z+=w1.z*kk.y; acc0.w+=w1.w*kk.y;
            acc1.x+=w1.x*kk.w; acc1.y+=w1.y*kk.w; acc1.z+=w1.z*kk.w; acc1.w+=w1.w*kk.w;
        }
        tot0.x+=acc0.x; tot0.y+=acc0.y; tot0.z+=acc0.z; tot0.w+=acc0.w;
        tot1.x+=acc1.x; tot1.y+=acc1.y; tot1.z+=acc1.z; tot1.w+=acc1.w;
    }
    const float nm0 = norm_s[q0], nm1 = norm_s[q1];
    const size_t base = (size_t)(blk * QBF) * COUT + (o4 << 2);
    *(float4*)(out + base + (size_t)q0 * COUT) =
        make_float4(tot0.x*nm0, tot0.y*nm0, tot0.z*nm0, tot0.w*nm0);
    *(float4*)(out + base + (size_t)q1 * COUT) =
        make_float4(tot1.x*nm1, tot1.y*nm1, tot1.z*nm1, tot1.w*nm1);
}

extern "C" void kernel_launch(void* const* d_in, const int* in_sizes, int n_in,
                              void* d_out, int out_size, void* d_ws, size_t ws_size,
                              hipStream_t stream) {
    const float* q_pts   = (const float*)d_in[0];
    const float* s_pts   = (const float*)d_in[1];
    const float* s_feats = (const float*)d_in[2];
    const int*   neigh   = (const int*)d_in[3];
    const float* W       = (const float*)d_in[4];
    const float* kpts    = (const float*)d_in[5];
    float* outp = (float*)d_out;

    dim3 mgrid((NQ + QB - 1) / QB);   // 1563
    dim3 mblock(512);

    if (ws_size >= WSB_END) {
        float* rs  = (float*)d_ws;
        short* whi = (short*)((char*)d_ws + WSB_HI);
        short* wlo = (short*)((char*)d_ws + WSB_LO);
        int rs_blocks = (MS * 8 + 255) / 256;
        hipLaunchKernelGGL(prep_basic, dim3(60 + rs_blocks), dim3(256), 0, stream,
                           s_feats, W, rs, whi, wlo);
        hipLaunchKernelGGL(kpconv_mfma, mgrid, mblock, 0, stream,
                           q_pts, s_pts, s_feats, neigh, kpts, rs, whi, wlo, outp);
    } else {
        hipLaunchKernelGGL(kpconv_fallback, dim3(NQ / 16), dim3(256), 0, stream,
                           q_pts, s_pts, s_feats, neigh, W, kpts, outp);
    }
}